// Round 1
// baseline (147.753 us; speedup 1.0000x reference)
//
#include <hip/hip_runtime.h>
#include <stdint.h>

typedef __attribute__((ext_vector_type(8))) __bf16 bf16x8;
typedef __attribute__((ext_vector_type(4))) float f32x4;
typedef unsigned short u16;

__device__ __forceinline__ u16 f2bf(float f) {
  unsigned u = __builtin_bit_cast(unsigned, f);
  unsigned r = 0x7FFFu + ((u >> 16) & 1u);
  return (u16)((u + r) >> 16);
}

__device__ __forceinline__ void gload16(const void* g, void* l) {
  __builtin_amdgcn_global_load_lds(
      (__attribute__((address_space(1))) void*)(g),
      (__attribute__((address_space(3))) void*)(l),
      16, 0, 0);
}

// ---- deg / rsqrt -----------------------------------------------------------
__global__ void row_deg_k(const float* __restrict__ adj, float* __restrict__ dis, int N) {
  int row = blockIdx.x;
  const float4* a = (const float4*)(adj + (size_t)row * N);
  float s = 0.f;
  for (int j = threadIdx.x; j < N / 4; j += 256) {
    float4 v = a[j];
    s += v.x + v.y + v.z + v.w;
  }
#pragma unroll
  for (int off = 32; off > 0; off >>= 1) s += __shfl_down(s, off, 64);
  __shared__ float wsum[4];
  if ((threadIdx.x & 63) == 0) wsum[threadIdx.x >> 6] = s;
  __syncthreads();
  if (threadIdx.x == 0) {
    float t = wsum[0] + wsum[1] + wsum[2] + wsum[3];
    dis[row] = (t > 0.f) ? (1.0f / sqrtf(t)) : 0.f;
  }
}

// ---- fp32 -> bf16 vectorized ----------------------------------------------
__global__ void conv_bf16_k(const float* __restrict__ in, u16* __restrict__ o, int n4) {
  int i = blockIdx.x * 256 + threadIdx.x;
  if (i >= n4) return;
  float4 v = ((const float4*)in)[i];
  ushort4 u;
  u.x = f2bf(v.x); u.y = f2bf(v.y); u.z = f2bf(v.z); u.w = f2bf(v.w);
  ((ushort4*)o)[i] = u;
}

// ---- W [512,512] -> W^T bf16 ----------------------------------------------
__global__ void conv_wt_k(const float* __restrict__ w, u16* __restrict__ wt) {
  int idx = blockIdx.x * 256 + threadIdx.x;  // 262144 total
  int i = idx >> 9, o = idx & 511;
  wt[o * 512 + i] = f2bf(w[idx]);
}

// ---- norm_adj bf16 ---------------------------------------------------------
__global__ void make_nadj_k(const float* __restrict__ adj, const float* __restrict__ dis,
                            u16* __restrict__ o, int N) {
  int idx = blockIdx.x * 256 + threadIdx.x;  // per float4, N*N/4 total
  int i = idx >> 9;                          // N/4 = 512 float4 per row
  int j4 = (idx & 511) * 4;
  float di = dis[i];
  float4 a = ((const float4*)adj)[idx];
  ushort4 u;
  u.x = f2bf(a.x * di * dis[j4 + 0]);
  u.y = f2bf(a.y * di * dis[j4 + 1]);
  u.z = f2bf(a.z * di * dis[j4 + 2]);
  u.w = f2bf(a.w * di * dis[j4 + 3]);
  ((ushort4*)o)[idx] = u;
}

// ---- bf16 GEMM: C = A[M,K] * Bt[N,K]^T ------------------------------------
// 128x128 tile, BK=32, 4 waves, each wave 64x64 (4x4 frags of 16x16x32 MFMA).
// EPI=0: write bf16 transposed C^T [N][ldc]   (for support^T)
// EPI=1: write f32 C [M][ldc] + bias
template <int EPI>
__launch_bounds__(256, 2)
__global__ void gemm_bt_k(const u16* __restrict__ A, int lda,
                          const u16* __restrict__ Bt, int ldb,
                          void* __restrict__ Cv, int ldc,
                          const float* __restrict__ bias, int K,
                          size_t zStrideBt, size_t zStrideC) {
  __shared__ __align__(16) u16 sA[128 * 32];
  __shared__ __align__(16) u16 sB[128 * 32];
  const int tid = threadIdx.x;
  const int lane = tid & 63;
  const int wid = tid >> 6;
  const int rowBase = blockIdx.x * 128;
  const int colBase = blockIdx.y * 128;
  Bt += (size_t)blockIdx.z * zStrideBt;

  const int wrow = (wid >> 1) * 64;
  const int wcol = (wid & 1) * 64;

  f32x4 acc[4][4] = {};

  const int r0 = lane >> 2;
  const int kk0 = (lane & 3) * 8;

  for (int k0 = 0; k0 < K; k0 += 32) {
    __syncthreads();
#pragma unroll
    for (int j = 0; j < 2; ++j) {
      int c = j * 4 + wid;
      int r = c * 16 + r0;
      gload16(&A[(size_t)(rowBase + r) * lda + k0 + kk0], &sA[c * 512 + lane * 8]);
      gload16(&Bt[(size_t)(colBase + r) * ldb + k0 + kk0], &sB[c * 512 + lane * 8]);
    }
    __syncthreads();
    bf16x8 af[4], bfr[4];
#pragma unroll
    for (int m = 0; m < 4; ++m) {
      int row = wrow + m * 16 + (lane & 15);
      af[m] = *reinterpret_cast<const bf16x8*>(&sA[row * 32 + (lane >> 4) * 8]);
    }
#pragma unroll
    for (int n = 0; n < 4; ++n) {
      int row = wcol + n * 16 + (lane & 15);
      bfr[n] = *reinterpret_cast<const bf16x8*>(&sB[row * 32 + (lane >> 4) * 8]);
    }
#pragma unroll
    for (int m = 0; m < 4; ++m)
#pragma unroll
      for (int n = 0; n < 4; ++n)
        acc[m][n] = __builtin_amdgcn_mfma_f32_16x16x32_bf16(af[m], bfr[n], acc[m][n], 0, 0, 0);
  }

  if (EPI == 0) {
    u16* C = (u16*)Cv;
#pragma unroll
    for (int m = 0; m < 4; ++m) {
      int r = rowBase + wrow + m * 16 + ((lane >> 4) << 2);
#pragma unroll
      for (int n = 0; n < 4; ++n) {
        int cc = colBase + wcol + n * 16 + (lane & 15);
        ushort4 v;
        v.x = f2bf(acc[m][n][0]); v.y = f2bf(acc[m][n][1]);
        v.z = f2bf(acc[m][n][2]); v.w = f2bf(acc[m][n][3]);
        *reinterpret_cast<ushort4*>(&C[(size_t)cc * ldc + r]) = v;
      }
    }
  } else {
    float* C = (float*)Cv + (size_t)blockIdx.z * zStrideC;
#pragma unroll
    for (int n = 0; n < 4; ++n) {
      int cc = colBase + wcol + n * 16 + (lane & 15);
      float bv = bias[cc];
#pragma unroll
      for (int m = 0; m < 4; ++m) {
        int r = rowBase + wrow + m * 16 + ((lane >> 4) << 2);
#pragma unroll
        for (int j = 0; j < 4; ++j)
          C[(size_t)(r + j) * ldc + cc] = acc[m][n][j] + bv;
      }
    }
  }
}

extern "C" void kernel_launch(void* const* d_in, const int* in_sizes, int n_in,
                              void* d_out, int out_size, void* d_ws, size_t ws_size,
                              hipStream_t stream) {
  const int B = 16, N = 2048, FIN = 512, FOUT = 512;
  const float* x    = (const float*)d_in[0];
  const float* adj  = (const float*)d_in[1];
  const float* w    = (const float*)d_in[2];
  const float* bias = (const float*)d_in[3];
  float* out = (float*)d_out;
  char* ws = (char*)d_ws;

  float* dis = (float*)ws;                       // 8 KB
  u16* wt    = (u16*)(ws + 8192);                // 512 KB  W^T [FOUT][FIN]
  u16* nadj  = (u16*)(ws + 532480);              // 8 MB    [N][N]
  u16* xb    = (u16*)(ws + 8921088);             // 32 MB   [B*N][FIN]
  u16* st    = (u16*)(ws + 42475520);            // 32 MB   support^T [FOUT][B*N]

  row_deg_k<<<N, 256, 0, stream>>>(adj, dis, N);
  conv_bf16_k<<<(B * N * FIN / 4 + 255) / 256, 256, 0, stream>>>(x, xb, B * N * FIN / 4);
  conv_wt_k<<<(FIN * FOUT) / 256, 256, 0, stream>>>(w, wt);
  make_nadj_k<<<(N * N / 4) / 256, 256, 0, stream>>>(adj, dis, nadj, N);

  // GEMM1: support^T[o][g] : A=xb [32768,512], Bt=wt [512,512]
  gemm_bt_k<0><<<dim3((B * N) / 128, FOUT / 128, 1), 256, 0, stream>>>(
      xb, FIN, wt, FIN, st, B * N, nullptr, FIN, 0, 0);

  // GEMM2: out[b] = nadj @ support[b] + bias : A=nadj [2048,2048],
  // Bt = st + b*2048 with ldb = 32768 (rows = o, K = m)
  gemm_bt_k<1><<<dim3(N / 128, FOUT / 128, B), 256, 0, stream>>>(
      nadj, N, st, B * N, out, FOUT, bias, N, (size_t)N, (size_t)N * FOUT);
}

// Round 2
// 130.285 us; speedup vs baseline: 1.1341x; 1.1341x over previous
//
#include <hip/hip_runtime.h>
#include <stdint.h>

typedef __attribute__((ext_vector_type(8))) __bf16 bf16x8;
typedef __attribute__((ext_vector_type(4))) float f32x4;
typedef unsigned short u16;

__device__ __forceinline__ u16 f2bf(float f) {
  unsigned u = __builtin_bit_cast(unsigned, f);
  unsigned r = 0x7FFFu + ((u >> 16) & 1u);
  return (u16)((u + r) >> 16);
}

__device__ __forceinline__ void gload16(const void* g, void* l) {
  __builtin_amdgcn_global_load_lds(
      (__attribute__((address_space(1))) void*)(g),
      (__attribute__((address_space(3))) void*)(l),
      16, 0, 0);
}

// ---- deg / rsqrt -----------------------------------------------------------
__global__ void row_deg_k(const float* __restrict__ adj, float* __restrict__ dis, int N) {
  int row = blockIdx.x;
  const float4* a = (const float4*)(adj + (size_t)row * N);
  float s = 0.f;
  for (int j = threadIdx.x; j < N / 4; j += 256) {
    float4 v = a[j];
    s += v.x + v.y + v.z + v.w;
  }
#pragma unroll
  for (int off = 32; off > 0; off >>= 1) s += __shfl_down(s, off, 64);
  __shared__ float wsum[4];
  if ((threadIdx.x & 63) == 0) wsum[threadIdx.x >> 6] = s;
  __syncthreads();
  if (threadIdx.x == 0) {
    float t = wsum[0] + wsum[1] + wsum[2] + wsum[3];
    dis[row] = (t > 0.f) ? (1.0f / sqrtf(t)) : 0.f;
  }
}

// ---- fp32 -> bf16 vectorized ----------------------------------------------
__global__ void conv_bf16_k(const float* __restrict__ in, u16* __restrict__ o, int n4) {
  int i = blockIdx.x * 256 + threadIdx.x;
  if (i >= n4) return;
  float4 v = ((const float4*)in)[i];
  ushort4 u;
  u.x = f2bf(v.x); u.y = f2bf(v.y); u.z = f2bf(v.z); u.w = f2bf(v.w);
  ((ushort4*)o)[i] = u;
}

// ---- W [512,512] -> W^T bf16 ----------------------------------------------
__global__ void conv_wt_k(const float* __restrict__ w, u16* __restrict__ wt) {
  int idx = blockIdx.x * 256 + threadIdx.x;  // 262144 total
  int i = idx >> 9, o = idx & 511;
  wt[o * 512 + i] = f2bf(w[idx]);
}

// ---- norm_adj bf16 ---------------------------------------------------------
__global__ void make_nadj_k(const float* __restrict__ adj, const float* __restrict__ dis,
                            u16* __restrict__ o, int N) {
  int idx = blockIdx.x * 256 + threadIdx.x;  // per float4, N*N/4 total
  int i = idx >> 9;                          // N/4 = 512 float4 per row
  int j4 = (idx & 511) * 4;
  float di = dis[i];
  float4 a = ((const float4*)adj)[idx];
  ushort4 u;
  u.x = f2bf(a.x * di * dis[j4 + 0]);
  u.y = f2bf(a.y * di * dis[j4 + 1]);
  u.z = f2bf(a.z * di * dis[j4 + 2]);
  u.w = f2bf(a.w * di * dis[j4 + 3]);
  ((ushort4*)o)[idx] = u;
}

// ---- 256x256 8-phase bf16 GEMM: C = A[M,K] * Bt[N,K]^T ---------------------
// 512 threads (8 waves, 2Mx4N), BK=64, 128 KiB LDS double-buffered,
// per-lane-source XOR swizzle (kk ^= ((row>>2)&3)<<4), counted vmcnt(6),
// setprio around MFMA clusters. EPI=0: bf16 C^T write; EPI=1: f32 C + bias.
template <int EPI>
__launch_bounds__(512, 2)
__global__ void gemm256_k(const u16* __restrict__ A, int lda,
                          const u16* __restrict__ Bt, int ldb,
                          void* __restrict__ Cv, int ldc,
                          const float* __restrict__ bias, int K,
                          int nMT, int nNT, size_t zBt, size_t zC) {
  __shared__ __align__(16) u16 lds[65536];  // A:[2][256][64] @0, B:[2][256][64] @32768

  const int tid = threadIdx.x;
  const int lane = tid & 63;
  const int wid = tid >> 6;
  const int wr = wid >> 2;   // 0..1  (M)
  const int wc = wid & 3;    // 0..3  (N)

  // bijective XCD swizzle (gridDim.x == 256, divisible by 8)
  const int flat = blockIdx.x;
  const int wg = (flat & 7) * ((int)gridDim.x >> 3) + (flat >> 3);
  const int m_t = wg % nMT;
  const int rest = wg / nMT;
  const int n_t = rest % nNT;
  const int b = rest / nNT;
  const int rowBase = m_t * 256;
  const int colBase = n_t * 256;
  const u16* Bb = Bt + (size_t)b * zBt;

  // staging: per-thread row lr, linear LDS kk, pre-swizzled global kk
  const int lr = tid >> 3;            // 0..63
  const int kkl = (tid & 7) * 8;      // 0..56
  const int kswz = kkl ^ (((lr >> 2) & 3) << 4);
  const u16* gA = A + (size_t)(rowBase + lr) * lda + kswz;
  const u16* gB = Bb + (size_t)(colBase + lr) * ldb + kswz;
  u16* lA = lds + lr * 64 + kkl;
  u16* lB = lds + 32768 + lr * 64 + kkl;

  // fragment reads: row = base + (lane&15), swizzled k offset
  const int fr = lane & 15;
  const int lswz = ((lane >> 2) & 3) << 4;
  const int kp0 = ((lane >> 4) * 8) ^ lswz;
  const int kp1 = (32 + (lane >> 4) * 8) ^ lswz;
  const u16* fA = lds + (wr * 128 + fr) * 64;
  const u16* fB = lds + 32768 + (wc * 64 + fr) * 64;

  f32x4 acc[8][4] = {};
  bf16x8 a0[4], a1[4], b0[4], b1[4];

  const int NT = K >> 6;

// A staged in interleaved halves: h covers rows {h*64..h*64+63} U {h*64+128..h*64+191}
// (matches mh read order: mh=0 rows read only in P1, mh=1 only in P3)
#define STAGE_A(d, h, t)                                                             \
  do {                                                                               \
    gload16(gA + (size_t)((h) * 64) * lda + (size_t)(t) * 64,                        \
            lA + (d) * 16384 + ((h) * 64) * 64);                                     \
    gload16(gA + (size_t)((h) * 64 + 128) * lda + (size_t)(t) * 64,                  \
            lA + (d) * 16384 + ((h) * 64 + 128) * 64);                               \
  } while (0)

#define STAGE_B(d, h, t)                                                             \
  do {                                                                               \
    gload16(gB + (size_t)((h) * 128) * ldb + (size_t)(t) * 64,                       \
            lB + (d) * 16384 + ((h) * 128) * 64);                                    \
    gload16(gB + (size_t)((h) * 128 + 64) * ldb + (size_t)(t) * 64,                  \
            lB + (d) * 16384 + ((h) * 128 + 64) * 64);                               \
  } while (0)

#define RD_A(mh, c)                                                                  \
  _Pragma("unroll") for (int m = 0; m < 4; ++m) {                                    \
    a0[m] = *(const bf16x8*)(fA + (c) * 16384 + (mh) * 4096 + m * 1024 + kp0);       \
    a1[m] = *(const bf16x8*)(fA + (c) * 16384 + (mh) * 4096 + m * 1024 + kp1);       \
  }

#define RD_B2(nlo, c)                                                                \
  _Pragma("unroll") for (int n = 0; n < 2; ++n) {                                    \
    b0[(nlo) + n] = *(const bf16x8*)(fB + (c) * 16384 + ((nlo) + n) * 1024 + kp0);   \
    b1[(nlo) + n] = *(const bf16x8*)(fB + (c) * 16384 + ((nlo) + n) * 1024 + kp1);   \
  }

#define SYNC_PRE()                                                                   \
  __builtin_amdgcn_sched_barrier(0);                                                 \
  __builtin_amdgcn_s_barrier();                                                      \
  asm volatile("s_waitcnt lgkmcnt(0)" ::: "memory");                                 \
  __builtin_amdgcn_sched_barrier(0);                                                 \
  __builtin_amdgcn_s_setprio(1)

#define SYNC_POST()                                                                  \
  __builtin_amdgcn_s_setprio(0);                                                     \
  __builtin_amdgcn_sched_barrier(0);                                                 \
  __builtin_amdgcn_s_barrier()

#define MFMA_Q(mh, nlo)                                                              \
  _Pragma("unroll") for (int m = 0; m < 4; ++m) {                                    \
    _Pragma("unroll") for (int n = 0; n < 2; ++n) {                                  \
      acc[(mh) * 4 + m][(nlo) + n] = __builtin_amdgcn_mfma_f32_16x16x32_bf16(        \
          a0[m], b0[(nlo) + n], acc[(mh) * 4 + m][(nlo) + n], 0, 0, 0);              \
      acc[(mh) * 4 + m][(nlo) + n] = __builtin_amdgcn_mfma_f32_16x16x32_bf16(        \
          a1[m], b1[(nlo) + n], acc[(mh) * 4 + m][(nlo) + n], 0, 0, 0);              \
    }                                                                                \
  }

  // prologue: tile0 complete (4 halves) + tile1 {Ah0', Bh0, Bh1}; 14 loads/thread
  {
    const int t1 = (NT > 1) ? 1 : 0;
    STAGE_A(0, 0, 0);
    STAGE_A(0, 1, 0);
    STAGE_B(0, 0, 0);
    STAGE_B(0, 1, 0);
    STAGE_A(1, 0, t1);
    STAGE_B(1, 0, t1);
    STAGE_B(1, 1, t1);
    asm volatile("s_waitcnt vmcnt(6)" ::: "memory");  // tile0's 8 loads landed
    __builtin_amdgcn_s_barrier();
  }

  for (int t = 0; t < NT; ++t) {
    const int c = t & 1;
    const int cn = c ^ 1;
    const int tn1 = (t + 1 < NT) ? t + 1 : NT - 1;  // clamped: garbage lands in dead regions
    const int tn2 = (t + 2 < NT) ? t + 2 : NT - 1;

    // P1: quadrant (mh=0, n0-1); stage (t+1).Ah1' -> buf cn (last read iter t-1 P3)
    RD_A(0, c);
    RD_B2(0, c);
    STAGE_A(cn, 1, tn1);
    SYNC_PRE();
    MFMA_Q(0, 0);
    SYNC_POST();

    // P2: (mh=0, n2-3); stage (t+2).Ah0' -> buf c (last read this iter P1)
    RD_B2(2, c);
    STAGE_A(c, 0, tn2);
    SYNC_PRE();
    MFMA_Q(0, 2);
    SYNC_POST();

    // P3: (mh=1, n2-3); stage (t+2).Bh0 -> buf c (B reads done after P2)
    RD_A(1, c);
    STAGE_B(c, 0, tn2);
    SYNC_PRE();
    MFMA_Q(1, 2);
    SYNC_POST();

    // P4: (mh=1, n0-1), no ds_reads; stage (t+2).Bh1; counted vmcnt gates tile t+1
    STAGE_B(c, 1, tn2);
    SYNC_PRE();
    MFMA_Q(1, 0);
    asm volatile("s_waitcnt vmcnt(6)" ::: "memory");  // before barrier: t+1 fully landed
    SYNC_POST();
  }
  asm volatile("s_waitcnt vmcnt(0)" ::: "memory");  // drain clamped prefetches

  if (EPI == 0) {
    u16* C = (u16*)Cv;
#pragma unroll
    for (int am = 0; am < 8; ++am) {
      const int r = rowBase + wr * 128 + (am >> 2) * 64 + (am & 3) * 16 + (lane >> 4) * 4;
#pragma unroll
      for (int n = 0; n < 4; ++n) {
        const int cc = colBase + wc * 64 + n * 16 + (lane & 15);
        ushort4 v;
        v.x = f2bf(acc[am][n][0]);
        v.y = f2bf(acc[am][n][1]);
        v.z = f2bf(acc[am][n][2]);
        v.w = f2bf(acc[am][n][3]);
        *reinterpret_cast<ushort4*>(&C[(size_t)cc * ldc + r]) = v;
      }
    }
  } else {
    float* C = (float*)Cv + (size_t)b * zC;
#pragma unroll
    for (int n = 0; n < 4; ++n) {
      const int cc = colBase + wc * 64 + n * 16 + (lane & 15);
      const float bv = bias[cc];
#pragma unroll
      for (int am = 0; am < 8; ++am) {
        const int r = rowBase + wr * 128 + (am >> 2) * 64 + (am & 3) * 16 + (lane >> 4) * 4;
#pragma unroll
        for (int j = 0; j < 4; ++j)
          C[(size_t)(r + j) * ldc + cc] = acc[am][n][j] + bv;
      }
    }
  }
#undef STAGE_A
#undef STAGE_B
#undef RD_A
#undef RD_B2
#undef SYNC_PRE
#undef SYNC_POST
#undef MFMA_Q
}

extern "C" void kernel_launch(void* const* d_in, const int* in_sizes, int n_in,
                              void* d_out, int out_size, void* d_ws, size_t ws_size,
                              hipStream_t stream) {
  const int B = 16, N = 2048, FIN = 512, FOUT = 512;
  const float* x    = (const float*)d_in[0];
  const float* adj  = (const float*)d_in[1];
  const float* w    = (const float*)d_in[2];
  const float* bias = (const float*)d_in[3];
  float* out = (float*)d_out;
  char* ws = (char*)d_ws;

  float* dis = (float*)ws;                       // 8 KB
  u16* wt    = (u16*)(ws + 8192);                // 512 KB  W^T [FOUT][FIN]
  u16* nadj  = (u16*)(ws + 532480);              // 8 MB    [N][N]
  u16* xb    = (u16*)(ws + 8921088);             // 32 MB   [B*N][FIN]
  u16* st    = (u16*)(ws + 42475520);            // 32 MB   support^T [FOUT][B*N]

  row_deg_k<<<N, 256, 0, stream>>>(adj, dis, N);
  conv_bf16_k<<<(B * N * FIN / 4 + 255) / 256, 256, 0, stream>>>(x, xb, B * N * FIN / 4);
  conv_wt_k<<<(FIN * FOUT) / 256, 256, 0, stream>>>(w, wt);
  make_nadj_k<<<(N * N / 4) / 256, 256, 0, stream>>>(adj, dis, nadj, N);

  // GEMM1: support^T = (xb @ wt^T)^T : A=xb [32768,512], Bt=wt [512,512]
  // grid = 128*2*1 = 256 blocks
  gemm256_k<0><<<dim3(256), 512, 0, stream>>>(
      xb, FIN, wt, FIN, st, B * N, nullptr, FIN, 128, 2, 0, 0);

  // GEMM2: out[b] = nadj @ support[b] + bias : A=nadj [2048,2048],
  // Bt = st + b*2048 (ldb=32768, K=N), C = out + b*N*FOUT
  // grid = 8*2*16 = 256 blocks
  gemm256_k<1><<<dim3(256), 512, 0, stream>>>(
      nadj, N, st, B * N, out, FOUT, bias, N, 8, 2,
      (size_t)N, (size_t)N * FOUT);
}

// Round 3
// 126.442 us; speedup vs baseline: 1.1685x; 1.0304x over previous
//
#include <hip/hip_runtime.h>
#include <stdint.h>

typedef __attribute__((ext_vector_type(8))) __bf16 bf16x8;
typedef __attribute__((ext_vector_type(4))) float f32x4;
typedef unsigned short u16;

__device__ __forceinline__ u16 f2bf(float f) {
  unsigned u = __builtin_bit_cast(unsigned, f);
  unsigned r = 0x7FFFu + ((u >> 16) & 1u);
  return (u16)((u + r) >> 16);
}

__device__ __forceinline__ void gload16(const void* g, void* l) {
  __builtin_amdgcn_global_load_lds(
      (__attribute__((address_space(1))) void*)(g),
      (__attribute__((address_space(3))) void*)(l),
      16, 0, 0);
}

// ---- deg / rsqrt -----------------------------------------------------------
__global__ void row_deg_k(const float* __restrict__ adj, float* __restrict__ dis, int N) {
  int row = blockIdx.x;
  const float4* a = (const float4*)(adj + (size_t)row * N);
  float s = 0.f;
  for (int j = threadIdx.x; j < N / 4; j += 256) {
    float4 v = a[j];
    s += v.x + v.y + v.z + v.w;
  }
#pragma unroll
  for (int off = 32; off > 0; off >>= 1) s += __shfl_down(s, off, 64);
  __shared__ float wsum[4];
  if ((threadIdx.x & 63) == 0) wsum[threadIdx.x >> 6] = s;
  __syncthreads();
  if (threadIdx.x == 0) {
    float t = wsum[0] + wsum[1] + wsum[2] + wsum[3];
    dis[row] = (t > 0.f) ? (1.0f / sqrtf(t)) : 0.f;
  }
}

// ---- fp32 -> bf16 vectorized ----------------------------------------------
__global__ void conv_bf16_k(const float* __restrict__ in, u16* __restrict__ o, int n4) {
  int i = blockIdx.x * 256 + threadIdx.x;
  if (i >= n4) return;
  float4 v = ((const float4*)in)[i];
  ushort4 u;
  u.x = f2bf(v.x); u.y = f2bf(v.y); u.z = f2bf(v.z); u.w = f2bf(v.w);
  ((ushort4*)o)[i] = u;
}

// ---- W [512,512] -> W^T bf16 ----------------------------------------------
__global__ void conv_wt_k(const float* __restrict__ w, u16* __restrict__ wt) {
  int idx = blockIdx.x * 256 + threadIdx.x;  // 262144 total
  int i = idx >> 9, o = idx & 511;
  wt[o * 512 + i] = f2bf(w[idx]);
}

// ---- norm_adj bf16 ---------------------------------------------------------
__global__ void make_nadj_k(const float* __restrict__ adj, const float* __restrict__ dis,
                            u16* __restrict__ o, int N) {
  int idx = blockIdx.x * 256 + threadIdx.x;  // per float4, N*N/4 total
  int i = idx >> 9;                          // N/4 = 512 float4 per row
  int j4 = (idx & 511) * 4;
  float di = dis[i];
  float4 a = ((const float4*)adj)[idx];
  ushort4 u;
  u.x = f2bf(a.x * di * dis[j4 + 0]);
  u.y = f2bf(a.y * di * dis[j4 + 1]);
  u.z = f2bf(a.z * di * dis[j4 + 2]);
  u.w = f2bf(a.w * di * dis[j4 + 3]);
  ((ushort4*)o)[idx] = u;
}

// ---- 256x256 bf16 GEMM, 1 barrier/K-tile, reg ping-pong pipeline -----------
// C = A[M,K] * Bt[N,K]^T. 512 threads (8 waves, 2Mx4N), BK=64, 128 KiB LDS
// double-buffered, source-side XOR swizzle (elem ^= ((row>>2)&3)<<4).
// Per tile: issue-early stage of t+1 (8 global_load_lds), then 4 phases where
// phase p issues phase p+1's ds_reads before phase p's 16-MFMA cluster
// (LDS pipe drains under the MFMA pipe); single vmcnt(0)+barrier per tile.
// EPI=0: bf16 C^T write; EPI=1: f32 C + bias.
template <int EPI>
__launch_bounds__(512, 2)
__global__ void gemm256_k(const u16* __restrict__ A, int lda,
                          const u16* __restrict__ Bt, int ldb,
                          void* __restrict__ Cv, int ldc,
                          const float* __restrict__ bias, int K,
                          int nMT, int nNT, size_t zBt, size_t zC) {
  __shared__ __align__(16) u16 lds[65536];  // A:[2][256][64] @0, B:[2][256][64] @32768

  const int tid = threadIdx.x;
  const int lane = tid & 63;
  const int wid = tid >> 6;
  const int wr = wid >> 2;   // 0..1  (M)
  const int wc = wid & 3;    // 0..3  (N)

  // bijective XCD swizzle (gridDim.x == 256, divisible by 8)
  const int flat = blockIdx.x;
  const int wg = (flat & 7) * ((int)gridDim.x >> 3) + (flat >> 3);
  const int m_t = wg % nMT;
  const int rest = wg / nMT;
  const int n_t = rest % nNT;
  const int b = rest / nNT;
  const int rowBase = m_t * 256;
  const int colBase = n_t * 256;
  const u16* Bb = Bt + (size_t)b * zBt;

  // staging: per-thread row lr, linear LDS col kkl, pre-swizzled global col
  const int lr = tid >> 3;            // 0..63
  const int kkl = (tid & 7) * 8;      // 0..56
  const int kswz = kkl ^ (((lr >> 2) & 3) << 4);
  const u16* gA = A + (size_t)(rowBase + lr) * lda + kswz;
  const u16* gB = Bb + (size_t)(colBase + lr) * ldb + kswz;
  u16* lA = lds + lr * 64 + kkl;
  u16* lB = lds + 32768 + lr * 64 + kkl;

  // fragment reads: row = base + (lane&15), swizzled k offset
  const int fr = lane & 15;
  const int lswz = ((lane >> 2) & 3) << 4;
  const int kp0 = ((lane >> 4) * 8) ^ lswz;
  const int kp1 = (32 + (lane >> 4) * 8) ^ lswz;
  const u16* fA = lds + (wr * 128 + fr) * 64;
  const u16* fB = lds + 32768 + (wc * 64 + fr) * 64;

  f32x4 acc[8][4] = {};
  bf16x8 As0[4], As1[4], Bs0[4], Bs1[4];

  const int NT = K >> 6;

#define STAGE_ALL(d, t)                                                              \
  _Pragma("unroll") for (int r4 = 0; r4 < 4; ++r4) {                                 \
    gload16(gA + (size_t)(r4 * 64) * lda + (size_t)(t) * 64,                         \
            lA + (d) * 16384 + r4 * 4096);                                           \
    gload16(gB + (size_t)(r4 * 64) * ldb + (size_t)(t) * 64,                         \
            lB + (d) * 16384 + r4 * 4096);                                           \
  }

#define RD_A(dst, mh, kh, c)                                                         \
  _Pragma("unroll") for (int m = 0; m < 4; ++m)                                      \
    dst[m] = *(const bf16x8*)(fA + (c) * 16384 + (mh) * 4096 + m * 1024 + kp##kh);

#define RD_B(dst, kh, c)                                                             \
  _Pragma("unroll") for (int n = 0; n < 4; ++n)                                      \
    dst[n] = *(const bf16x8*)(fB + (c) * 16384 + n * 1024 + kp##kh);

#define MFMA_P(mh, A_, B_)                                                           \
  _Pragma("unroll") for (int m = 0; m < 4; ++m)                                      \
    _Pragma("unroll") for (int n = 0; n < 4; ++n)                                    \
      acc[(mh) * 4 + m][n] = __builtin_amdgcn_mfma_f32_16x16x32_bf16(                \
          A_[m], B_[n], acc[(mh) * 4 + m][n], 0, 0, 0);

  // prologue: stage tile0 into buf0, drain, sync
  STAGE_ALL(0, 0);
  asm volatile("s_waitcnt vmcnt(0)" ::: "memory");
  __builtin_amdgcn_s_barrier();

  for (int t = 0; t < NT; ++t) {
    const int c = t & 1;
    const int cn = c ^ 1;
    const int tn = (t + 1 < NT) ? t + 1 : NT - 1;  // tail clamp: staged, never read

    __builtin_amdgcn_sched_barrier(0);
    // issue-early: next tile's 8 global_load_lds (vmcnt drained at tile end)
    STAGE_ALL(cn, tn);
    // P0 fragments
    RD_A(As0, 0, 0, c);
    RD_B(Bs0, 0, c);
    __builtin_amdgcn_sched_barrier(0);

    // P0: prefetch P1 frags, then MFMA (mh0, kh0)
    RD_A(As1, 1, 0, c);
    MFMA_P(0, As0, Bs0);
    __builtin_amdgcn_sched_barrier(0);

    // P1: prefetch P2 frags, then MFMA (mh1, kh0)
    RD_A(As0, 0, 1, c);
    RD_B(Bs1, 1, c);
    MFMA_P(1, As1, Bs0);
    __builtin_amdgcn_sched_barrier(0);

    // P2: prefetch P3 frags, then MFMA (mh0, kh1)
    RD_A(As1, 1, 1, c);
    MFMA_P(0, As0, Bs1);
    __builtin_amdgcn_sched_barrier(0);

    // P3: MFMA (mh1, kh1)
    MFMA_P(1, As1, Bs1);
    __builtin_amdgcn_sched_barrier(0);

    asm volatile("s_waitcnt vmcnt(0)" ::: "memory");  // t+1 fully landed (issued ~1 tile ago)
    __builtin_amdgcn_sched_barrier(0);
    __builtin_amdgcn_s_barrier();
  }

  if (EPI == 0) {
    u16* C = (u16*)Cv;
#pragma unroll
    for (int am = 0; am < 8; ++am) {
      const int r = rowBase + wr * 128 + (am >> 2) * 64 + (am & 3) * 16 + (lane >> 4) * 4;
#pragma unroll
      for (int n = 0; n < 4; ++n) {
        const int cc = colBase + wc * 64 + n * 16 + (lane & 15);
        ushort4 v;
        v.x = f2bf(acc[am][n][0]);
        v.y = f2bf(acc[am][n][1]);
        v.z = f2bf(acc[am][n][2]);
        v.w = f2bf(acc[am][n][3]);
        *reinterpret_cast<ushort4*>(&C[(size_t)cc * ldc + r]) = v;
      }
    }
  } else {
    float* C = (float*)Cv + (size_t)b * zC;
#pragma unroll
    for (int n = 0; n < 4; ++n) {
      const int cc = colBase + wc * 64 + n * 16 + (lane & 15);
      const float bv = bias[cc];
#pragma unroll
      for (int am = 0; am < 8; ++am) {
        const int r = rowBase + wr * 128 + (am >> 2) * 64 + (am & 3) * 16 + (lane >> 4) * 4;
#pragma unroll
        for (int j = 0; j < 4; ++j)
          C[(size_t)(r + j) * ldc + cc] = acc[am][n][j] + bv;
      }
    }
  }
#undef STAGE_ALL
#undef RD_A
#undef RD_B
#undef MFMA_P
}

extern "C" void kernel_launch(void* const* d_in, const int* in_sizes, int n_in,
                              void* d_out, int out_size, void* d_ws, size_t ws_size,
                              hipStream_t stream) {
  const int B = 16, N = 2048, FIN = 512, FOUT = 512;
  const float* x    = (const float*)d_in[0];
  const float* adj  = (const float*)d_in[1];
  const float* w    = (const float*)d_in[2];
  const float* bias = (const float*)d_in[3];
  float* out = (float*)d_out;
  char* ws = (char*)d_ws;

  float* dis = (float*)ws;                       // 8 KB
  u16* wt    = (u16*)(ws + 8192);                // 512 KB  W^T [FOUT][FIN]
  u16* nadj  = (u16*)(ws + 532480);              // 8 MB    [N][N]
  u16* xb    = (u16*)(ws + 8921088);             // 32 MB   [B*N][FIN]
  u16* st    = (u16*)(ws + 42475520);            // 32 MB   support^T [FOUT][B*N]

  row_deg_k<<<N, 256, 0, stream>>>(adj, dis, N);
  conv_bf16_k<<<(B * N * FIN / 4 + 255) / 256, 256, 0, stream>>>(x, xb, B * N * FIN / 4);
  conv_wt_k<<<(FIN * FOUT) / 256, 256, 0, stream>>>(w, wt);
  make_nadj_k<<<(N * N / 4) / 256, 256, 0, stream>>>(adj, dis, nadj, N);

  // GEMM1: support^T = (xb @ wt^T)^T : A=xb [32768,512], Bt=wt [512,512]
  // grid = 128*2*1 = 256 blocks
  gemm256_k<0><<<dim3(256), 512, 0, stream>>>(
      xb, FIN, wt, FIN, st, B * N, nullptr, FIN, 128, 2, 0, 0);

  // GEMM2: out[b] = nadj @ support[b] + bias : A=nadj [2048,2048],
  // Bt = st + b*2048 (ldb=32768, K=N), C = out + b*N*FOUT
  // grid = 8*2*16 = 256 blocks
  gemm256_k<1><<<dim3(256), 512, 0, stream>>>(
      nadj, N, st, B * N, out, FOUT, bias, N, 8, 2,
      (size_t)N, (size_t)N * FOUT);
}

// Round 5
// 125.221 us; speedup vs baseline: 1.1799x; 1.0098x over previous
//
#include <hip/hip_runtime.h>
#include <stdint.h>

typedef __attribute__((ext_vector_type(8))) __bf16 bf16x8;
typedef __attribute__((ext_vector_type(4))) float f32x4;
typedef unsigned short u16;

__device__ __forceinline__ u16 f2bf(float f) {
  unsigned u = __builtin_bit_cast(unsigned, f);
  unsigned r = 0x7FFFu + ((u >> 16) & 1u);
  return (u16)((u + r) >> 16);
}

__device__ __forceinline__ void gload16(const void* g, void* l) {
  __builtin_amdgcn_global_load_lds(
      (__attribute__((address_space(1))) void*)(g),
      (__attribute__((address_space(3))) void*)(l),
      16, 0, 0);
}

// ---- deg / rsqrt -----------------------------------------------------------
__global__ void row_deg_k(const float* __restrict__ adj, float* __restrict__ dis, int N) {
  int row = blockIdx.x;
  const float4* a = (const float4*)(adj + (size_t)row * N);
  float s = 0.f;
  for (int j = threadIdx.x; j < N / 4; j += 256) {
    float4 v = a[j];
    s += v.x + v.y + v.z + v.w;
  }
#pragma unroll
  for (int off = 32; off > 0; off >>= 1) s += __shfl_down(s, off, 64);
  __shared__ float wsum[4];
  if ((threadIdx.x & 63) == 0) wsum[threadIdx.x >> 6] = s;
  __syncthreads();
  if (threadIdx.x == 0) {
    float t = wsum[0] + wsum[1] + wsum[2] + wsum[3];
    dis[row] = (t > 0.f) ? (1.0f / sqrtf(t)) : 0.f;
  }
}

// ---- fp32 -> bf16 vectorized ----------------------------------------------
__global__ void conv_bf16_k(const float* __restrict__ in, u16* __restrict__ o, int n4) {
  int i = blockIdx.x * 256 + threadIdx.x;
  if (i >= n4) return;
  float4 v = ((const float4*)in)[i];
  ushort4 u;
  u.x = f2bf(v.x); u.y = f2bf(v.y); u.z = f2bf(v.z); u.w = f2bf(v.w);
  ((ushort4*)o)[i] = u;
}

// ---- W [512,512] -> W^T bf16 ----------------------------------------------
__global__ void conv_wt_k(const float* __restrict__ w, u16* __restrict__ wt) {
  int idx = blockIdx.x * 256 + threadIdx.x;  // 262144 total
  int i = idx >> 9, o = idx & 511;
  wt[o * 512 + i] = f2bf(w[idx]);
}

// ---- norm_adj bf16 ---------------------------------------------------------
__global__ void make_nadj_k(const float* __restrict__ adj, const float* __restrict__ dis,
                            u16* __restrict__ o, int N) {
  int idx = blockIdx.x * 256 + threadIdx.x;  // per float4, N*N/4 total
  int i = idx >> 9;                          // N/4 = 512 float4 per row
  int j4 = (idx & 511) * 4;
  float di = dis[i];
  float4 a = ((const float4*)adj)[idx];
  ushort4 u;
  u.x = f2bf(a.x * di * dis[j4 + 0]);
  u.y = f2bf(a.y * di * dis[j4 + 1]);
  u.z = f2bf(a.z * di * dis[j4 + 2]);
  u.w = f2bf(a.w * di * dis[j4 + 3]);
  ((ushort4*)o)[idx] = u;
}

// ---- 256x256 bf16 GEMM, 2 barriers/K-tile, cross-tile frag carry -----------
// C = A[M,K] * Bt[N,K]^T. 512 threads (8 waves, 2Mx4N), BK=64, 128 KiB LDS
// double-buffered. Swizzle: elem ^= (row&7)<<3 (G4), applied on the staging
// global source and on ds_read addrs (both-sides). Every phase overlaps
// 4-8 ds_reads with a 16-MFMA cluster. Cross-wave safety: carried reads of
// buf cn happen only after {own vmcnt(0) -> s_barrier} (global_load_lds
// completion is per-wave; the barrier publishes all waves' stages).
// EPI=0: bf16 C^T write; EPI=1: f32 C + bias.
template <int EPI>
__launch_bounds__(512, 2)
__global__ void gemm256_k(const u16* __restrict__ A, int lda,
                          const u16* __restrict__ Bt, int ldb,
                          void* __restrict__ Cv, int ldc,
                          const float* __restrict__ bias, int K,
                          int nMT, int nNT, size_t zBt, size_t zC) {
  __shared__ __align__(16) u16 lds[65536];  // A:[2][256][64] @0, B:[2][256][64] @32768

  const int tid = threadIdx.x;
  const int lane = tid & 63;
  const int wid = tid >> 6;
  const int wr = wid >> 2;   // 0..1  (M)
  const int wc = wid & 3;    // 0..3  (N)

  // bijective XCD swizzle (gridDim.x == 256, divisible by 8)
  const int flat = blockIdx.x;
  const int wg = (flat & 7) * ((int)gridDim.x >> 3) + (flat >> 3);
  const int m_t = wg % nMT;
  const int rest = wg / nMT;
  const int n_t = rest % nNT;
  const int b = rest / nNT;
  const int rowBase = m_t * 256;
  const int colBase = n_t * 256;
  const u16* Bb = Bt + (size_t)b * zBt;

  // staging: per-thread row lr, linear LDS col kkl, pre-swizzled global col
  const int lr = tid >> 3;            // 0..63
  const int kkl = (tid & 7) * 8;      // 0..56
  const int kswz = kkl ^ ((lr & 7) << 3);
  const u16* gA = A + (size_t)(rowBase + lr) * lda + kswz;
  const u16* gB = Bb + (size_t)(colBase + lr) * ldb + kswz;
  u16* lA = lds + lr * 64 + kkl;
  u16* lB = lds + 32768 + lr * 64 + kkl;

  // fragment reads: row = base + (lane&15); granule XOR on row bits 0-2
  const int fr = lane & 15;
  const int rswz = (lane & 7) << 3;
  const int kp0 = ((lane >> 4) * 8) ^ rswz;
  const int kp1 = (32 | ((lane >> 4) * 8)) ^ rswz;
  const u16* fA = lds + (wr * 128 + fr) * 64;
  const u16* fB = lds + 32768 + (wc * 64 + fr) * 64;

  f32x4 acc[8][4] = {};
  bf16x8 As0[4], As1[4], Bs0[4], Bs1[4];

  const int NT = K >> 6;

#define STAGE_ALL(d, t)                                                              \
  _Pragma("unroll") for (int r4 = 0; r4 < 4; ++r4) {                                 \
    gload16(gA + (size_t)(r4 * 64) * lda + (size_t)(t) * 64,                         \
            lA + (d) * 16384 + r4 * 4096);                                           \
    gload16(gB + (size_t)(r4 * 64) * ldb + (size_t)(t) * 64,                         \
            lB + (d) * 16384 + r4 * 4096);                                           \
  }

#define RD_A4(dst, mh, kp, c)                                                        \
  _Pragma("unroll") for (int m = 0; m < 4; ++m)                                      \
    dst[m] = *(const bf16x8*)(fA + (c) * 16384 + (mh) * 4096 + m * 1024 + (kp));

#define RD_B4(dst, kp, c)                                                            \
  _Pragma("unroll") for (int n = 0; n < 4; ++n)                                      \
    dst[n] = *(const bf16x8*)(fB + (c) * 16384 + n * 1024 + (kp));

#define RD_B2(dst, nlo, kp, c)                                                       \
  _Pragma("unroll") for (int n = 0; n < 2; ++n)                                      \
    dst[(nlo) + n] = *(const bf16x8*)(fB + (c) * 16384 + ((nlo) + n) * 1024 + (kp));

#define MFMA_P(mh, A_, B_)                                                           \
  __builtin_amdgcn_sched_barrier(0);                                                 \
  __builtin_amdgcn_s_setprio(1);                                                     \
  _Pragma("unroll") for (int m = 0; m < 4; ++m)                                      \
    _Pragma("unroll") for (int n = 0; n < 4; ++n)                                    \
      acc[(mh) * 4 + m][n] = __builtin_amdgcn_mfma_f32_16x16x32_bf16(                \
          A_[m], B_[n], acc[(mh) * 4 + m][n], 0, 0, 0);                              \
  __builtin_amdgcn_s_setprio(0);                                                     \
  __builtin_amdgcn_sched_barrier(0)

  // prologue: stage tile0 into buf0, drain, publish, pre-read P0 fragments
  STAGE_ALL(0, 0);
  asm volatile("s_waitcnt vmcnt(0)" ::: "memory");
  __builtin_amdgcn_s_barrier();
  RD_A4(As0, 0, kp0, 0);
  RD_B4(Bs0, kp0, 0);

  for (int t = 0; t < NT; ++t) {
    const int c = t & 1;
    const int cn = c ^ 1;
    const int tn = (t + 1 < NT) ? t + 1 : NT - 1;  // tail clamp: staged, never consumed

    __builtin_amdgcn_sched_barrier(0);
    STAGE_ALL(cn, tn);  // issue-early; drained at this tile's P3 (3 phases later)

    // P0: prefetch (mh1,kh0); MFMA (mh0,kh0)   [As0,Bs0 carried across barrier]
    RD_A4(As1, 1, kp0, c);
    MFMA_P(0, As0, Bs0);

    // P1: prefetch (mh0,kh1) + B(kh1) lo; MFMA (mh1,kh0)
    RD_A4(As0, 0, kp1, c);
    RD_B2(Bs1, 0, kp1, c);
    MFMA_P(1, As1, Bs0);

    // P2: prefetch (mh1,kh1) + B(kh1) hi; MFMA (mh0,kh1)
    RD_A4(As1, 1, kp1, c);
    RD_B2(Bs1, 2, kp1, c);
    MFMA_P(0, As0, Bs1);

    // P3: own stages drained + barrier publishes ALL waves' stages of buf cn;
    //     then carried reads of tile t+1's P0 frags overlap the last MFMA.
    __builtin_amdgcn_sched_barrier(0);
    asm volatile("s_waitcnt vmcnt(0)" ::: "memory");
    __builtin_amdgcn_sched_barrier(0);
    __builtin_amdgcn_s_barrier();
    __builtin_amdgcn_sched_barrier(0);
    RD_A4(As0, 0, kp0, cn);
    RD_B4(Bs0, kp0, cn);
    MFMA_P(1, As1, Bs1);

    // tile-end: all waves' buf-c reads consumed (lgkm waits precede the MFMA
    // above) before next iteration's stage overwrites buf c.
    __builtin_amdgcn_sched_barrier(0);
    __builtin_amdgcn_s_barrier();
  }
  asm volatile("s_waitcnt vmcnt(0)" ::: "memory");  // drain clamped tail stages

  if (EPI == 0) {
    u16* C = (u16*)Cv;
#pragma unroll
    for (int am = 0; am < 8; ++am) {
      const int r = rowBase + wr * 128 + (am >> 2) * 64 + (am & 3) * 16 + (lane >> 4) * 4;
#pragma unroll
      for (int n = 0; n < 4; ++n) {
        const int cc = colBase + wc * 64 + n * 16 + (lane & 15);
        ushort4 v;
        v.x = f2bf(acc[am][n][0]);
        v.y = f2bf(acc[am][n][1]);
        v.z = f2bf(acc[am][n][2]);
        v.w = f2bf(acc[am][n][3]);
        *reinterpret_cast<ushort4*>(&C[(size_t)cc * ldc + r]) = v;
      }
    }
  } else {
    float* C = (float*)Cv + (size_t)b * zC;
#pragma unroll
    for (int n = 0; n < 4; ++n) {
      const int cc = colBase + wc * 64 + n * 16 + (lane & 15);
      const float bv = bias[cc];
#pragma unroll
      for (int am = 0; am < 8; ++am) {
        const int r = rowBase + wr * 128 + (am >> 2) * 64 + (am & 3) * 16 + (lane >> 4) * 4;
#pragma unroll
        for (int j = 0; j < 4; ++j)
          C[(size_t)(r + j) * ldc + cc] = acc[am][n][j] + bv;
      }
    }
  }
#undef STAGE_ALL
#undef RD_A4
#undef RD_B4
#undef RD_B2
#undef MFMA_P
}

extern "C" void kernel_launch(void* const* d_in, const int* in_sizes, int n_in,
                              void* d_out, int out_size, void* d_ws, size_t ws_size,
                              hipStream_t stream) {
  const int B = 16, N = 2048, FIN = 512, FOUT = 512;
  const float* x    = (const float*)d_in[0];
  const float* adj  = (const float*)d_in[1];
  const float* w    = (const float*)d_in[2];
  const float* bias = (const float*)d_in[3];
  float* out = (float*)d_out;
  char* ws = (char*)d_ws;

  float* dis = (float*)ws;                       // 8 KB
  u16* wt    = (u16*)(ws + 8192);                // 512 KB  W^T [FOUT][FIN]
  u16* nadj  = (u16*)(ws + 532480);              // 8 MB    [N][N]
  u16* xb    = (u16*)(ws + 8921088);             // 32 MB   [B*N][FIN]
  u16* st    = (u16*)(ws + 42475520);            // 32 MB   support^T [FOUT][B*N]

  row_deg_k<<<N, 256, 0, stream>>>(adj, dis, N);
  conv_bf16_k<<<(B * N * FIN / 4 + 255) / 256, 256, 0, stream>>>(x, xb, B * N * FIN / 4);
  conv_wt_k<<<(FIN * FOUT) / 256, 256, 0, stream>>>(w, wt);
  make_nadj_k<<<(N * N / 4) / 256, 256, 0, stream>>>(adj, dis, nadj, N);

  // GEMM1: support^T = (xb @ wt^T)^T : A=xb [32768,512], Bt=wt [512,512]
  // grid = 128*2*1 = 256 blocks
  gemm256_k<0><<<dim3(256), 512, 0, stream>>>(
      xb, FIN, wt, FIN, st, B * N, nullptr, FIN, 128, 2, 0, 0);

  // GEMM2: out[b] = nadj @ support[b] + bias : A=nadj [2048,2048],
  // Bt = st + b*2048 (ldb=32768, K=N), C = out + b*N*FOUT
  // grid = 8*2*16 = 256 blocks
  gemm256_k<1><<<dim3(256), 512, 0, stream>>>(
      nadj, N, st, B * N, out, FOUT, bias, N, 8, 2,
      (size_t)N, (size_t)N * FOUT);
}